// Round 4
// baseline (1023.889 us; speedup 1.0000x reference)
//
#include <hip/hip_runtime.h>
#include <hip/hip_bf16.h>

// GCN_5016521802361: 2x SAGEConv(aggr='lstm', project=True), N=50000, D=16, F=128, C=40.
// Round 4: break the barrier-drain. Step-loop barrier is now lgkmcnt-only
// (CK "block_sync_lds": s_waitcnt lgkmcnt(0); s_barrier) so global Y-prefetch
// loads stay in flight across steps; Y-prefetch deepened to 4 steps (4 cyclic
// register slots, unroll-4 so slots are static). Rest unchanged from round 3.

typedef __hip_bfloat16 bf16;
typedef __attribute__((ext_vector_type(8))) short short8;
typedef __attribute__((ext_vector_type(4))) short short4v;
typedef __attribute__((ext_vector_type(4))) float floatx4;

__device__ __forceinline__ float bf2f(bf16 v) { return __bfloat162float(v); }
__device__ __forceinline__ bf16  f2bf(float v) { return __float2bfloat16(v); }
__device__ __forceinline__ float bfs2f(short s) {
    union { float f; unsigned u; } v; v.u = ((unsigned)(unsigned short)s) << 16; return v.f;
}
__device__ __forceinline__ short f2bfs(float v) {
    bf16 b = __float2bfloat16(v); return *(short*)&b;
}
__device__ __forceinline__ float sigm(float x)  { return __builtin_amdgcn_rcpf(1.f + __expf(-x)); }
__device__ __forceinline__ float tanh_(float x) { return 1.f - 2.f * __builtin_amdgcn_rcpf(__expf(2.f * x) + 1.f); }

// barrier that does NOT drain vmcnt (LDS-only ordering) — CK block_sync_lds idiom
__device__ __forceinline__ void sync_lds_only() {
    asm volatile("s_waitcnt lgkmcnt(0)\n\ts_barrier" ::: "memory");
}

__global__ void detect_dtype(const unsigned short* __restrict__ xb, int* __restrict__ flag) {
    int cnt = 0;
    for (int i = threadIdx.x; i < 1024; i += 64) {
        int e = (xb[i] >> 7) & 0xFF;
        cnt += (e >= 0xC8);   // impossible exponent for N(0,1) bf16 data
    }
#pragma unroll
    for (int off = 32; off; off >>= 1) cnt += __shfl_down(cnt, off);
    if (threadIdx.x == 0) *flag = (cnt >= 16) ? 1 : 0;   // 1 => inputs are float32
}

struct Cvt { const void* src; bf16* dst; int n; };
struct CvtAll { Cvt t[19]; };

__global__ void convert_inputs(CvtAll ca, const int* __restrict__ flag) {
    const bool isf32 = (*flag != 0);
    const int stride = gridDim.x * blockDim.x;
    const int tid0 = blockIdx.x * blockDim.x + threadIdx.x;
#pragma unroll 1
    for (int k = 0; k < 19; k++) {
        const int n = ca.t[k].n;
        const float* sf = (const float*)ca.t[k].src;
        const bf16*  sb = (const bf16*)ca.t[k].src;
        bf16* d = ca.t[k].dst;
        for (int i = tid0; i < n; i += stride)
            d[i] = isf32 ? f2bf(sf[i]) : sb[i];
    }
}

template <int NCT, bool RELU, bool BIAS2, bool DUAL, bool OUTF>
__global__ __launch_bounds__(256, 1) void gemm_bias(
    const bf16* __restrict__ A, const bf16* __restrict__ B,
    const bf16* __restrict__ bias, const bf16* __restrict__ bias2,
    const bf16* __restrict__ A2, const bf16* __restrict__ B2,
    void* __restrict__ Cv, const int* __restrict__ oflag,
    int N, int nbt, int ldc)
{
    const int tid = threadIdx.x;
    const int w = tid >> 6, l = tid & 63, q = l >> 4, lid = l & 15;
    const int rowbase = blockIdx.x * 64 + w * 16;
    const int colslice = blockIdx.y * 128;

    int arow = rowbase + lid;
    if (arow >= N) arow = N - 1;

    floatx4 acc[NCT];
#pragma unroll
    for (int ct = 0; ct < NCT; ct++) acc[ct] = (floatx4)(0.f);

    short8 bfrag[NCT][4];
#pragma unroll
    for (int ct = 0; ct < NCT; ct++) {
        int j = colslice + ct * 16 + lid;
        if (j >= nbt) j = nbt - 1;
#pragma unroll
        for (int kt = 0; kt < 4; kt++)
            bfrag[ct][kt] = *(const short8*)(B + (size_t)j * 128 + kt * 32 + q * 8);
    }
#pragma unroll
    for (int kt = 0; kt < 4; kt++) {
        short8 af = *(const short8*)(A + (size_t)arow * 128 + kt * 32 + q * 8);
#pragma unroll
        for (int ct = 0; ct < NCT; ct++)
            acc[ct] = __builtin_amdgcn_mfma_f32_16x16x32_bf16(af, bfrag[ct][kt], acc[ct], 0, 0, 0);
    }
    if constexpr (DUAL) {
#pragma unroll
        for (int ct = 0; ct < NCT; ct++) {
            int j = colslice + ct * 16 + lid;
            if (j >= nbt) j = nbt - 1;
#pragma unroll
            for (int kt = 0; kt < 4; kt++)
                bfrag[ct][kt] = *(const short8*)(B2 + (size_t)j * 128 + kt * 32 + q * 8);
        }
#pragma unroll
        for (int kt = 0; kt < 4; kt++) {
            short8 af = *(const short8*)(A2 + (size_t)arow * 128 + kt * 32 + q * 8);
#pragma unroll
            for (int ct = 0; ct < NCT; ct++)
                acc[ct] = __builtin_amdgcn_mfma_f32_16x16x32_bf16(af, bfrag[ct][kt], acc[ct], 0, 0, 0);
        }
    }
    bool of32 = false;
    if constexpr (OUTF) of32 = (*oflag != 0);
#pragma unroll
    for (int ct = 0; ct < NCT; ct++) {
        int cg = colslice + ct * 16 + lid;
        int cb = cg < nbt ? cg : nbt - 1;
        float bv = bf2f(bias[cb]);
        if constexpr (BIAS2) bv += bf2f(bias2[cb]);
#pragma unroll
        for (int r = 0; r < 4; r++) {
            int row = rowbase + q * 4 + r;
            float v = acc[ct][r] + bv;
            if constexpr (RELU) v = fmaxf(v, 0.f);
            if (row < N && cg < nbt) {
                size_t idx = (size_t)row * ldc + cg;
                if constexpr (OUTF) {
                    if (of32) ((float*)Cv)[idx] = v;
                    else      ((bf16*)Cv)[idx] = f2bf(v);
                } else {
                    ((bf16*)Cv)[idx] = f2bf(v);
                }
            }
        }
    }
}

// ---------------------------------------------------------------------------
// LSTM neighbor aggregation, transposed recurrence G^T = Whh * h^T.
// Block = 16 nodes, 256 thr (4 waves). Wave w owns hidden cols [32w,32w+32).
// Whh A-frags VGPR-resident; h via LDS (lgkm-only barrier); c in regs.
// Y gather: 8 x dwordx2 per thread per step, prefetched FOUR steps ahead in
// 4 cyclic register slots; barriers do not drain vmcnt, so the loads overlap
// 4 full steps of MFMA+gate work across the whole block.
// ---------------------------------------------------------------------------
__global__ __launch_bounds__(256, 2) void lstm_aggr(
    const bf16* __restrict__ Y,     // [N,512] pre-activations incl. both biases
    const int* __restrict__ esrc,   // [N,16]
    const bf16* __restrict__ Whh,   // [512,128]
    bf16* __restrict__ aggr,        // [N,128] out: final h
    int N)
{
    __shared__ alignas(16) bf16 hb[2][16][136];
    __shared__ int srcl[16][16];    // [t][node]

    const int tid = threadIdx.x;
    const int w = tid >> 6, l = tid & 63, q = l >> 4, lid = l & 15;
    const int nodebase = blockIdx.x * 16;   // N = 50000 = 3125*16, exact

    {
        int node = tid >> 4, t = tid & 15;
        srcl[t][node] = esrc[(size_t)(nodebase + node) * 16 + t];
    }
    for (int i = tid; i < 16 * 136; i += 256) ((short*)hb[0])[i] = 0;

    // Whh A-fragments: wf[hl][g][kt]; A-row = gatecol = (2w+hl+8g)*16 + lid
    short8 wf[2][4][4];
#pragma unroll
    for (int hl = 0; hl < 2; hl++)
#pragma unroll
        for (int g = 0; g < 4; g++) {
            int gc = (2 * w + hl + 8 * g) * 16 + lid;
#pragma unroll
            for (int kt = 0; kt < 4; kt++)
                wf[hl][g][kt] = *(const short8*)(Whh + (size_t)gc * 128 + kt * 32 + q * 8);
        }

    float c[2][4];
#pragma unroll
    for (int hl = 0; hl < 2; hl++)
#pragma unroll
        for (int r = 0; r < 4; r++) c[hl][r] = 0.f;

    __syncthreads();   // full sync once: srcl/hb visible before preload

    // 4-deep cyclic Y prefetch: slot = t & 3
    short4v yv[4][2][4];
#pragma unroll
    for (int pt = 0; pt < 4; pt++) {
        int s0 = srcl[pt][lid];
        const bf16* yb = Y + (size_t)s0 * 512 + q * 4;
#pragma unroll
        for (int hl = 0; hl < 2; hl++)
#pragma unroll
            for (int g = 0; g < 4; g++)
                yv[pt][hl][g] = *(const short4v*)(yb + (2 * w + hl + 8 * g) * 16);
    }

#pragma unroll 4
    for (int t = 0; t < 16; t++) {
        const int sl = t & 3;            // static under unroll-4
        const int cur = t & 1, nxt = cur ^ 1;

        // acc init from prefetched Y (loaded 4 steps ago; vmcnt wait here only)
        floatx4 acc[2][4];
#pragma unroll
        for (int hl = 0; hl < 2; hl++)
#pragma unroll
            for (int g = 0; g < 4; g++)
#pragma unroll
                for (int r = 0; r < 4; r++)
                    acc[hl][g][r] = bfs2f(yv[sl][hl][g][r]);

        // refill this slot for t+4 (stays in flight across the lgkm-only barriers)
        if (t < 12) {
            int sn = srcl[t + 4][lid];
            const bf16* yb = Y + (size_t)sn * 512 + q * 4;
#pragma unroll
            for (int hl = 0; hl < 2; hl++)
#pragma unroll
                for (int g = 0; g < 4; g++)
                    yv[sl][hl][g] = *(const short4v*)(yb + (2 * w + hl + 8 * g) * 16);
        }

        // G^T += Whh * h^T : B-frag = h[node=lid][k] via ds_read_b128
#pragma unroll
        for (int kt = 0; kt < 4; kt++) {
            short8 bh = *(const short8*)&hb[cur][lid][kt * 32 + q * 8];
#pragma unroll
            for (int hl = 0; hl < 2; hl++)
#pragma unroll
                for (int g = 0; g < 4; g++)
                    acc[hl][g] = __builtin_amdgcn_mfma_f32_16x16x32_bf16(wf[hl][g][kt], bh, acc[hl][g], 0, 0, 0);
        }

        // gates (i,f,g,o); h' cols hc = 32w+16hl+q*4+r for node lid
#pragma unroll
        for (int hl = 0; hl < 2; hl++) {
            short4v hv;
#pragma unroll
            for (int r = 0; r < 4; r++) {
                float i_ = sigm(acc[hl][0][r]);
                float f_ = sigm(acc[hl][1][r]);
                float g_ = tanh_(acc[hl][2][r]);
                float o_ = sigm(acc[hl][3][r]);
                float cn = f_ * c[hl][r] + i_ * g_;
                c[hl][r] = cn;
                hv[r] = f2bfs(o_ * tanh_(cn));
            }
            if (t < 15) {
                *(short4v*)&hb[nxt][lid][32 * w + 16 * hl + 4 * q] = hv;
            } else {
                *(short4v*)(aggr + (size_t)(nodebase + lid) * 128 + 32 * w + 16 * hl + 4 * q) = hv;
            }
        }
        sync_lds_only();   // LDS ordering only — Y prefetch stays outstanding
    }
}

extern "C" void kernel_launch(void* const* d_in, const int* in_sizes, int n_in,
                              void* d_out, int out_size, void* d_ws, size_t ws_size,
                              hipStream_t stream)
{
    const int N = 50000;
    const int* es = (const int*)d_in[1];
    char* ws = (char*)d_ws;

    // converted bf16 copies of the 19 used float tensors @[0,15MB)
    static const int idxs[19] = {0, 8,9,10,11,12,13,14,15,16, 17,18,19,20,21,22,23,24,25};
    bf16* conv[19];
    size_t off = 0;
    CvtAll ca;
    for (int k = 0; k < 19; k++) {
        conv[k] = (bf16*)ws + off;
        ca.t[k].src = d_in[idxs[k]];
        ca.t[k].dst = conv[k];
        ca.t[k].n = in_sizes[idxs[k]];
        off += (size_t)((in_sizes[idxs[k]] + 63) & ~63);
    }
    int* flag = (int*)(ws + ((size_t)15 << 20));
    bf16* xp   = (bf16*)(ws + ((size_t)16 << 20));   // [N,128], reused as aggr
    bf16* Y    = (bf16*)(ws + ((size_t)30 << 20));   // [N,512]
    bf16* h1   = (bf16*)(ws + ((size_t)84 << 20));   // [N,128]
    bf16* aggr = xp;

    const bf16 *xc  = conv[0];
    const bf16 *Wp1 = conv[1],  *bp1 = conv[2],  *Wih1 = conv[3],  *Whh1 = conv[4];
    const bf16 *bih1 = conv[5], *bhh1 = conv[6], *Wl1 = conv[7],   *bl1 = conv[8],  *Wr1 = conv[9];
    const bf16 *Wp2 = conv[10], *bp2 = conv[11], *Wih2 = conv[12], *Whh2 = conv[13];
    const bf16 *bih2 = conv[14], *bhh2 = conv[15], *Wl2 = conv[16], *bl2 = conv[17], *Wr2 = conv[18];

    dim3 blk(256);
    const int gx = (N + 63) / 64;    // 782
    const int gl = N / 16;           // 3125 (exact)

    detect_dtype<<<dim3(1), dim3(64), 0, stream>>>((const unsigned short*)d_in[0], flag);
    convert_inputs<<<dim3(1024), blk, 0, stream>>>(ca, flag);

    // ---- layer 1 ----
    gemm_bias<8, true, false, false, false><<<dim3(gx, 1), blk, 0, stream>>>(
        xc, Wp1, bp1, nullptr, nullptr, nullptr, xp, nullptr, N, 128, 128);
    gemm_bias<8, false, true, false, false><<<dim3(gx, 4), blk, 0, stream>>>(
        xp, Wih1, bih1, bhh1, nullptr, nullptr, Y, nullptr, N, 512, 512);
    lstm_aggr<<<dim3(gl), blk, 0, stream>>>(Y, es, Whh1, aggr, N);
    gemm_bias<8, true, false, true, false><<<dim3(gx, 1), blk, 0, stream>>>(
        aggr, Wl1, bl1, nullptr, xc, Wr1, h1, nullptr, N, 128, 128);

    // ---- layer 2 ----
    gemm_bias<8, true, false, false, false><<<dim3(gx, 1), blk, 0, stream>>>(
        h1, Wp2, bp2, nullptr, nullptr, nullptr, xp, nullptr, N, 128, 128);
    gemm_bias<8, false, true, false, false><<<dim3(gx, 4), blk, 0, stream>>>(
        xp, Wih2, bih2, bhh2, nullptr, nullptr, Y, nullptr, N, 512, 512);
    lstm_aggr<<<dim3(gl), blk, 0, stream>>>(Y, es, Whh2, aggr, N);
    gemm_bias<3, false, false, true, true><<<dim3(gx, 1), blk, 0, stream>>>(
        aggr, Wl2, bl2, nullptr, h1, Wr2, d_out, flag, N, 40, 40);
}

// Round 5
// 898.328 us; speedup vs baseline: 1.1398x; 1.1398x over previous
//
#include <hip/hip_runtime.h>
#include <hip/hip_bf16.h>

// GCN_5016521802361: 2x SAGEConv(aggr='lstm', project=True), N=50000, D=16, F=128, C=40.
// Round 5: round-3 structure (depth-2 Y prefetch, 116 VGPR, no spills) with ONE change:
// the per-step barrier is lgkmcnt-only (CK block_sync_lds) instead of __syncthreads(),
// so the Y-gather prefetch issued in step t stays in flight across the barrier and
// completes under step t's MFMA + gate VALU. Round-4's depth-4 prefetch spilled
// (WRITE_SIZE 12.5->155MB scratch) and is reverted.

typedef __hip_bfloat16 bf16;
typedef __attribute__((ext_vector_type(8))) short short8;
typedef __attribute__((ext_vector_type(4))) short short4v;
typedef __attribute__((ext_vector_type(4))) float floatx4;

__device__ __forceinline__ float bf2f(bf16 v) { return __bfloat162float(v); }
__device__ __forceinline__ bf16  f2bf(float v) { return __float2bfloat16(v); }
__device__ __forceinline__ float bfs2f(short s) {
    union { float f; unsigned u; } v; v.u = ((unsigned)(unsigned short)s) << 16; return v.f;
}
__device__ __forceinline__ short f2bfs(float v) {
    bf16 b = __float2bfloat16(v); return *(short*)&b;
}
__device__ __forceinline__ float sigm(float x)  { return __builtin_amdgcn_rcpf(1.f + __expf(-x)); }
__device__ __forceinline__ float tanh_(float x) { return 1.f - 2.f * __builtin_amdgcn_rcpf(__expf(2.f * x) + 1.f); }

// barrier that does NOT drain vmcnt (LDS-only ordering) — CK block_sync_lds idiom
__device__ __forceinline__ void sync_lds_only() {
    asm volatile("s_waitcnt lgkmcnt(0)\n\ts_barrier" ::: "memory");
}

__global__ void detect_dtype(const unsigned short* __restrict__ xb, int* __restrict__ flag) {
    int cnt = 0;
    for (int i = threadIdx.x; i < 1024; i += 64) {
        int e = (xb[i] >> 7) & 0xFF;
        cnt += (e >= 0xC8);   // impossible exponent for N(0,1) bf16 data
    }
#pragma unroll
    for (int off = 32; off; off >>= 1) cnt += __shfl_down(cnt, off);
    if (threadIdx.x == 0) *flag = (cnt >= 16) ? 1 : 0;   // 1 => inputs are float32
}

struct Cvt { const void* src; bf16* dst; int n; };
struct CvtAll { Cvt t[19]; };

__global__ void convert_inputs(CvtAll ca, const int* __restrict__ flag) {
    const bool isf32 = (*flag != 0);
    const int stride = gridDim.x * blockDim.x;
    const int tid0 = blockIdx.x * blockDim.x + threadIdx.x;
#pragma unroll 1
    for (int k = 0; k < 19; k++) {
        const int n = ca.t[k].n;
        const float* sf = (const float*)ca.t[k].src;
        const bf16*  sb = (const bf16*)ca.t[k].src;
        bf16* d = ca.t[k].dst;
        for (int i = tid0; i < n; i += stride)
            d[i] = isf32 ? f2bf(sf[i]) : sb[i];
    }
}

template <int NCT, bool RELU, bool BIAS2, bool DUAL, bool OUTF>
__global__ __launch_bounds__(256, 1) void gemm_bias(
    const bf16* __restrict__ A, const bf16* __restrict__ B,
    const bf16* __restrict__ bias, const bf16* __restrict__ bias2,
    const bf16* __restrict__ A2, const bf16* __restrict__ B2,
    void* __restrict__ Cv, const int* __restrict__ oflag,
    int N, int nbt, int ldc)
{
    const int tid = threadIdx.x;
    const int w = tid >> 6, l = tid & 63, q = l >> 4, lid = l & 15;
    const int rowbase = blockIdx.x * 64 + w * 16;
    const int colslice = blockIdx.y * 128;

    int arow = rowbase + lid;
    if (arow >= N) arow = N - 1;

    floatx4 acc[NCT];
#pragma unroll
    for (int ct = 0; ct < NCT; ct++) acc[ct] = (floatx4)(0.f);

    short8 bfrag[NCT][4];
#pragma unroll
    for (int ct = 0; ct < NCT; ct++) {
        int j = colslice + ct * 16 + lid;
        if (j >= nbt) j = nbt - 1;
#pragma unroll
        for (int kt = 0; kt < 4; kt++)
            bfrag[ct][kt] = *(const short8*)(B + (size_t)j * 128 + kt * 32 + q * 8);
    }
#pragma unroll
    for (int kt = 0; kt < 4; kt++) {
        short8 af = *(const short8*)(A + (size_t)arow * 128 + kt * 32 + q * 8);
#pragma unroll
        for (int ct = 0; ct < NCT; ct++)
            acc[ct] = __builtin_amdgcn_mfma_f32_16x16x32_bf16(af, bfrag[ct][kt], acc[ct], 0, 0, 0);
    }
    if constexpr (DUAL) {
#pragma unroll
        for (int ct = 0; ct < NCT; ct++) {
            int j = colslice + ct * 16 + lid;
            if (j >= nbt) j = nbt - 1;
#pragma unroll
            for (int kt = 0; kt < 4; kt++)
                bfrag[ct][kt] = *(const short8*)(B2 + (size_t)j * 128 + kt * 32 + q * 8);
        }
#pragma unroll
        for (int kt = 0; kt < 4; kt++) {
            short8 af = *(const short8*)(A2 + (size_t)arow * 128 + kt * 32 + q * 8);
#pragma unroll
            for (int ct = 0; ct < NCT; ct++)
                acc[ct] = __builtin_amdgcn_mfma_f32_16x16x32_bf16(af, bfrag[ct][kt], acc[ct], 0, 0, 0);
        }
    }
    bool of32 = false;
    if constexpr (OUTF) of32 = (*oflag != 0);
#pragma unroll
    for (int ct = 0; ct < NCT; ct++) {
        int cg = colslice + ct * 16 + lid;
        int cb = cg < nbt ? cg : nbt - 1;
        float bv = bf2f(bias[cb]);
        if constexpr (BIAS2) bv += bf2f(bias2[cb]);
#pragma unroll
        for (int r = 0; r < 4; r++) {
            int row = rowbase + q * 4 + r;
            float v = acc[ct][r] + bv;
            if constexpr (RELU) v = fmaxf(v, 0.f);
            if (row < N && cg < nbt) {
                size_t idx = (size_t)row * ldc + cg;
                if constexpr (OUTF) {
                    if (of32) ((float*)Cv)[idx] = v;
                    else      ((bf16*)Cv)[idx] = f2bf(v);
                } else {
                    ((bf16*)Cv)[idx] = f2bf(v);
                }
            }
        }
    }
}

// ---------------------------------------------------------------------------
// LSTM neighbor aggregation, transposed recurrence G^T = Whh * h^T.
// Block = 16 nodes, 256 thr (4 waves). Wave w owns hidden cols [32w,32w+32).
// Whh A-frags VGPR/AGPR-resident (128 regs); h via LDS; c in regs.
// Y gather: 8 x dwordx2 per thread per step, double-buffered one step ahead.
// Step barrier is lgkm-only so the prefetch stays in flight across it.
// ---------------------------------------------------------------------------
__global__ __launch_bounds__(256, 2) void lstm_aggr(
    const bf16* __restrict__ Y,     // [N,512] pre-activations incl. both biases
    const int* __restrict__ esrc,   // [N,16]
    const bf16* __restrict__ Whh,   // [512,128]
    bf16* __restrict__ aggr,        // [N,128] out: final h
    int N)
{
    __shared__ alignas(16) bf16 hb[2][16][136];
    __shared__ int srcl[16][16];    // [t][node]

    const int tid = threadIdx.x;
    const int w = tid >> 6, l = tid & 63, q = l >> 4, lid = l & 15;
    const int nodebase = blockIdx.x * 16;   // N = 50000 = 3125*16, exact

    {
        int node = tid >> 4, t = tid & 15;
        srcl[t][node] = esrc[(size_t)(nodebase + node) * 16 + t];
    }
    for (int i = tid; i < 16 * 136; i += 256) ((short*)hb[0])[i] = 0;

    // Whh A-fragments: wf[hl][g][kt]; A-row = gatecol = (2w+hl+8g)*16 + lid
    short8 wf[2][4][4];
#pragma unroll
    for (int hl = 0; hl < 2; hl++)
#pragma unroll
        for (int g = 0; g < 4; g++) {
            int gc = (2 * w + hl + 8 * g) * 16 + lid;
#pragma unroll
            for (int kt = 0; kt < 4; kt++)
                wf[hl][g][kt] = *(const short8*)(Whh + (size_t)gc * 128 + kt * 32 + q * 8);
        }

    float c[2][4];
#pragma unroll
    for (int hl = 0; hl < 2; hl++)
#pragma unroll
        for (int r = 0; r < 4; r++) c[hl][r] = 0.f;

    __syncthreads();   // full sync once: srcl/hb visible before preload

    // double-buffered Y prefetch: yv[buf][hl][g] = Y[s][(2w+hl+8g)*16 + q*4 .. +3]
    short4v yv[2][2][4];
    {
        int s0 = srcl[0][lid];
        const bf16* yb = Y + (size_t)s0 * 512 + q * 4;
#pragma unroll
        for (int hl = 0; hl < 2; hl++)
#pragma unroll
            for (int g = 0; g < 4; g++)
                yv[0][hl][g] = *(const short4v*)(yb + (2 * w + hl + 8 * g) * 16);
    }

#pragma unroll 2
    for (int t = 0; t < 16; t++) {
        const int cur = t & 1, nxt = cur ^ 1;

        // acc init from prefetched Y (vmcnt wait lands here, one step after issue)
        floatx4 acc[2][4];
#pragma unroll
        for (int hl = 0; hl < 2; hl++)
#pragma unroll
            for (int g = 0; g < 4; g++)
#pragma unroll
                for (int r = 0; r < 4; r++)
                    acc[hl][g][r] = bfs2f(yv[cur][hl][g][r]);

        // prefetch Y for t+1 — stays in flight across the lgkm-only barrier
        if (t < 15) {
            int sn = srcl[t + 1][lid];
            const bf16* yb = Y + (size_t)sn * 512 + q * 4;
#pragma unroll
            for (int hl = 0; hl < 2; hl++)
#pragma unroll
                for (int g = 0; g < 4; g++)
                    yv[nxt][hl][g] = *(const short4v*)(yb + (2 * w + hl + 8 * g) * 16);
        }

        // G^T += Whh * h^T : B-frag = h[node=lid][k] via ds_read_b128
#pragma unroll
        for (int kt = 0; kt < 4; kt++) {
            short8 bh = *(const short8*)&hb[cur][lid][kt * 32 + q * 8];
#pragma unroll
            for (int hl = 0; hl < 2; hl++)
#pragma unroll
                for (int g = 0; g < 4; g++)
                    acc[hl][g] = __builtin_amdgcn_mfma_f32_16x16x32_bf16(wf[hl][g][kt], bh, acc[hl][g], 0, 0, 0);
        }

        // gates (i,f,g,o); h' cols hc = 32w+16hl+q*4+r for node lid
#pragma unroll
        for (int hl = 0; hl < 2; hl++) {
            short4v hv;
#pragma unroll
            for (int r = 0; r < 4; r++) {
                float i_ = sigm(acc[hl][0][r]);
                float f_ = sigm(acc[hl][1][r]);
                float g_ = tanh_(acc[hl][2][r]);
                float o_ = sigm(acc[hl][3][r]);
                float cn = f_ * c[hl][r] + i_ * g_;
                c[hl][r] = cn;
                hv[r] = f2bfs(o_ * tanh_(cn));
            }
            if (t < 15) {
                *(short4v*)&hb[nxt][lid][32 * w + 16 * hl + 4 * q] = hv;
            } else {
                *(short4v*)(aggr + (size_t)(nodebase + lid) * 128 + 32 * w + 16 * hl + 4 * q) = hv;
            }
        }
        sync_lds_only();   // LDS ordering only — Y prefetch stays outstanding
    }
}

extern "C" void kernel_launch(void* const* d_in, const int* in_sizes, int n_in,
                              void* d_out, int out_size, void* d_ws, size_t ws_size,
                              hipStream_t stream)
{
    const int N = 50000;
    const int* es = (const int*)d_in[1];
    char* ws = (char*)d_ws;

    // converted bf16 copies of the 19 used float tensors @[0,15MB)
    static const int idxs[19] = {0, 8,9,10,11,12,13,14,15,16, 17,18,19,20,21,22,23,24,25};
    bf16* conv[19];
    size_t off = 0;
    CvtAll ca;
    for (int k = 0; k < 19; k++) {
        conv[k] = (bf16*)ws + off;
        ca.t[k].src = d_in[idxs[k]];
        ca.t[k].dst = conv[k];
        ca.t[k].n = in_sizes[idxs[k]];
        off += (size_t)((in_sizes[idxs[k]] + 63) & ~63);
    }
    int* flag = (int*)(ws + ((size_t)15 << 20));
    bf16* xp   = (bf16*)(ws + ((size_t)16 << 20));   // [N,128], reused as aggr
    bf16* Y    = (bf16*)(ws + ((size_t)30 << 20));   // [N,512]
    bf16* h1   = (bf16*)(ws + ((size_t)84 << 20));   // [N,128]
    bf16* aggr = xp;

    const bf16 *xc  = conv[0];
    const bf16 *Wp1 = conv[1],  *bp1 = conv[2],  *Wih1 = conv[3],  *Whh1 = conv[4];
    const bf16 *bih1 = conv[5], *bhh1 = conv[6], *Wl1 = conv[7],   *bl1 = conv[8],  *Wr1 = conv[9];
    const bf16 *Wp2 = conv[10], *bp2 = conv[11], *Wih2 = conv[12], *Whh2 = conv[13];
    const bf16 *bih2 = conv[14], *bhh2 = conv[15], *Wl2 = conv[16], *bl2 = conv[17], *Wr2 = conv[18];

    dim3 blk(256);
    const int gx = (N + 63) / 64;    // 782
    const int gl = N / 16;           // 3125 (exact)

    detect_dtype<<<dim3(1), dim3(64), 0, stream>>>((const unsigned short*)d_in[0], flag);
    convert_inputs<<<dim3(1024), blk, 0, stream>>>(ca, flag);

    // ---- layer 1 ----
    gemm_bias<8, true, false, false, false><<<dim3(gx, 1), blk, 0, stream>>>(
        xc, Wp1, bp1, nullptr, nullptr, nullptr, xp, nullptr, N, 128, 128);
    gemm_bias<8, false, true, false, false><<<dim3(gx, 4), blk, 0, stream>>>(
        xp, Wih1, bih1, bhh1, nullptr, nullptr, Y, nullptr, N, 512, 512);
    lstm_aggr<<<dim3(gl), blk, 0, stream>>>(Y, es, Whh1, aggr, N);
    gemm_bias<8, true, false, true, false><<<dim3(gx, 1), blk, 0, stream>>>(
        aggr, Wl1, bl1, nullptr, xc, Wr1, h1, nullptr, N, 128, 128);

    // ---- layer 2 ----
    gemm_bias<8, true, false, false, false><<<dim3(gx, 1), blk, 0, stream>>>(
        h1, Wp2, bp2, nullptr, nullptr, nullptr, xp, nullptr, N, 128, 128);
    gemm_bias<8, false, true, false, false><<<dim3(gx, 4), blk, 0, stream>>>(
        xp, Wih2, bih2, bhh2, nullptr, nullptr, Y, nullptr, N, 512, 512);
    lstm_aggr<<<dim3(gl), blk, 0, stream>>>(Y, es, Whh2, aggr, N);
    gemm_bias<3, false, false, true, true><<<dim3(gx, 1), blk, 0, stream>>>(
        aggr, Wl2, bl2, nullptr, h1, Wr2, d_out, flag, N, 40, 40);
}